// Round 5
// baseline (230.926 us; speedup 1.0000x reference)
//
#include <hip/hip_runtime.h>
#include <hip/hip_cooperative_groups.h>

namespace cg = cooperative_groups;

// Problem constants (fixed by setup_inputs in the reference).
#define BS 32
#define NG 64            // num_gt (== 64 -> one uint64 bitmask per (b, prior))
#define NP 8400          // num_priors
#define NTOPK 9
#define NUM_CLASSES 80
#define NCAND 27         // 3 levels * TOPK

#define NBLK 512         // 2 blocks/CU on 256 CUs -> cooperative co-residency
#define NTHR 256
#define CHUNK 525        // NP / 16 chunks per batch; 512 = 32 b * 16 chunks

// ---------------------------------------------------------------------------
// SINGLE cooperative dispatch. R1->R4 fit: controllable time ~= sum(kernel
// work) + ~12us per enqueued op; kernel work is small => minimize ops.
// Phases (grid.sync between):
//   0: zero posbits (replaces memset dispatch)
//   1: candidates — VERBATIM the R1/R4-verified wave-per-(b,g) body
//      (2048 waves == this grid exactly; R3 showed 32-block serial = 196us)
//   2: fused resolve+write — VERBATIM the R1-verified k_assign semantics
//      (R4 proved the divergent resolve inside the streamer is ~free)
// ---------------------------------------------------------------------------
__device__ __forceinline__ unsigned long long wave_min_u64_32(unsigned long long k) {
    #pragma unroll
    for (int off = 1; off < 32; off <<= 1) {
        unsigned long long o = __shfl_xor(k, off, 64);
        k = (o < k) ? o : k;
    }
    return k;   // lanes 0-31 hold min over lanes 0-31 (keys live in 0-24)
}

__global__ __launch_bounds__(NTHR, 2) void k_fused(
    const float4* __restrict__ gt_bboxes,    // (BS*NG)
    const float*  __restrict__ pad_flag,     // (BS*NG)
    const float4* __restrict__ priors,       // (NP)
    const int*    __restrict__ gt_labels,    // (BS*NG)
    const float4* __restrict__ pred_bboxes,  // (BS*NP)
    unsigned long long* __restrict__ posbits,// (BS*NP) workspace
    float* __restrict__ out)
{
    cg::grid_group grid = cg::this_grid();

    __shared__ float4 s_gt[NG];
    __shared__ int    s_lab[NG];
    __shared__ int    s_plab[CHUNK];
    __shared__ float  s_piou[CHUNK];

    const int tid  = threadIdx.x;
    const int gtid = blockIdx.x * NTHR + tid;

    // ---- Phase 0: zero posbits ----
    for (int i = gtid; i < BS * NP; i += NBLK * NTHR) posbits[i] = 0;
    grid.sync();

    // ---- Phase 1: candidates (verbatim R1/R4-verified body) ----
    {
        const int bg   = gtid >> 6;            // wave id = (b,g), 0..2047
        const int lane = tid & 63;
        const int b  = bg >> 6;
        const int g  = bg & 63;

        const float4 gt  = gt_bboxes[bg];      // wave-uniform broadcast load
        const float  pad = pad_flag[bg];
        const float  gcx = (gt.x + gt.z) * 0.5f;
        const float  gcy = (gt.y + gt.w) * 0.5f;
        const float  garea = (gt.z - gt.x) * (gt.w - gt.y);

        const float lvl_s[3] = {8.0f, 16.0f, 32.0f};
        const int   lvl_n[3] = {80, 40, 20};
        const int   lvl_b[3] = {0, 6400, 8000};

        float ov[NCAND];    // candidate IoUs, slot order (registers: static idx)
        int   ixs[NCAND];   // candidate prior indices
        float sum = 0.0f;

        const int dy5 = lane / 5;              // cell owned by this lane (lane<25)
        const int dx5 = lane - dy5 * 5;

        #pragma unroll
        for (int L = 0; L < 3; ++L) {
            const float s    = lvl_s[L];
            const int   n    = lvl_n[L];
            const int   base = lvl_b[L];

            int wx = (int)floorf(gcx / s) - 2;
            int wy = (int)floorf(gcy / s) - 2;
            wx = min(max(wx, 0), n - 5);
            wy = min(max(wy, 0), n - 5);

            // lane-parallel key build over the 5x5 window
            unsigned long long key = ~0ull;
            if (lane < 25) {
                const int   iy  = wy + dy5;
                const int   ix  = wx + dx5;
                const float py  = ((float)iy + 0.5f) * s;
                const float px  = ((float)ix + 0.5f) * s;
                const float ddx = gcx - px;
                const float ddy = gcy - py;
                const float d   = sqrtf(ddx * ddx + ddy * ddy);
                key = ((unsigned long long)__float_as_uint(d) << 32) |
                      (unsigned int)(base + iy * n + ix);
            }

            const float hx = s * 2.5f;
            #pragma unroll
            for (int q = 0; q < NTOPK; ++q) {
                const unsigned long long m = wave_min_u64_32(key);
                if (key == m) key = ~0ull;     // unique keys: one lane drops out

                // emit slot (ascending dist = lax.top_k order): IoU
                const int slot = L * NTOPK + q;
                const int idx  = (int)(m & 0xffffffffu);
                const int rel  = idx - base;
                const int iy   = rel / n;      // n compile-time constant
                const int ix   = rel - iy * n;
                const float px = ((float)ix + 0.5f) * s;
                const float py = ((float)iy + 0.5f) * s;
                const float px0 = px - hx, py0 = py - hx;
                const float px1 = px + hx, py1 = py + hx;
                float lx = fmaxf(gt.x, px0), ly = fmaxf(gt.y, py0);
                float rx = fminf(gt.z, px1), ry = fminf(gt.w, py1);
                float w = fmaxf(rx - lx, 0.0f), h = fmaxf(ry - ly, 0.0f);
                float ovl = w * h;
                float parea = (px1 - px0) * (py1 - py0);
                float o = ovl / fmaxf(garea + parea - ovl, 1e-6f);  // EPS_OVERLAPS
                ov[slot]  = o;
                ixs[slot] = idx;
                sum += o;                      // slot-order accumulation
            }
        }

        const float mean = sum / (float)NCAND;
        float var = 0.0f;
        #pragma unroll
        for (int i = 0; i < NCAND; ++i) {
            float d = ov[i] - mean;
            var += d * d;
        }
        const float thr = mean + sqrtf(var / (float)(NCAND - 1));   // std ddof=1

        if (pad > 0.0f && lane == 0) {         // single-lane pos-writes
            #pragma unroll
            for (int i = 0; i < NCAND; ++i) {
                if (ov[i] > thr) {
                    const int   L    = i / NTOPK;  // static per unrolled i
                    const float s    = lvl_s[L];
                    const int   n    = lvl_n[L];
                    const int   base = lvl_b[L];
                    const int idx = ixs[i];
                    const int rel = idx - base;
                    const int iy  = rel / n;
                    const int ix  = rel - iy * n;
                    const float px = ((float)ix + 0.5f) * s;  // cell center (exact)
                    const float py = ((float)iy + 0.5f) * s;
                    // prior center strictly inside gt box (> 1e-9)
                    float mm = fminf(fminf(px - gt.x, py - gt.y),
                                     fminf(gt.z - px, gt.w - py));
                    if (mm > 1e-9f) {
                        atomicOr(&posbits[(size_t)b * NP + idx], 1ull << g);
                    }
                }
            }
        }
    }
    grid.sync();

    // ---- Phase 2: fused resolve + write (verbatim R1 k_assign semantics) ----
    const int b     = blockIdx.x >> 4;         // 512 blocks = 32 b x 16 chunks
    const int chunk = blockIdx.x & 15;
    const int pbase = chunk * CHUNK;           // 16 * 525 = 8400 = NP exactly

    if (tid < NG) {
        s_gt[tid]  = gt_bboxes[b * NG + tid];
        s_lab[tid] = gt_labels[b * NG + tid];
    }
    __syncthreads();

    for (int pl = tid; pl < CHUNK; pl += NTHR) {
        const int p = pbase + pl;
        const size_t bp = (size_t)b * NP + p;
        unsigned long long mask = posbits[bp];
        int fg = __popcll(mask);
        int gidx = 0;

        if (fg > 1) {
            // conflict: argmax_g IoU(gt, prior_cell_box) over ALL gts,
            // first max wins (matches jnp.argmax(overlaps, axis=1)).
            float4 pr = priors[p];
            float hx = pr.z * 2.5f, hy = pr.w * 2.5f;
            float px0 = pr.x - hx, py0 = pr.y - hy, px1 = pr.x + hx, py1 = pr.y + hy;
            float parea = (px1 - px0) * (py1 - py0);
            float best = -1.0f;
            for (int gg = 0; gg < NG; ++gg) {
                float4 gtb = s_gt[gg];
                float lx = fmaxf(gtb.x, px0), ly = fmaxf(gtb.y, py0);
                float rx = fminf(gtb.z, px1), ry = fminf(gtb.w, py1);
                float w = fmaxf(rx - lx, 0.0f), h = fmaxf(ry - ly, 0.0f);
                float ovl = w * h;
                float ga = (gtb.z - gtb.x) * (gtb.w - gtb.y);
                float v = ovl / fmaxf(ga + parea - ovl, 1e-6f);
                if (v > best) { best = v; gidx = gg; }
            }
        } else if (fg == 1) {
            gidx = __ffsll((unsigned long long)mask) - 1;
        }

        const bool   fgm = fg > 0;
        const float4 gtb = s_gt[gidx];   // gidx==0 for background (ref: argmax of zeros)
        const int  label = fgm ? s_lab[gidx] : NUM_CLASSES;
        float iou_w = 0.0f;

        if (fgm) {
            float4 pb = pred_bboxes[bp];
            float lx = fmaxf(gtb.x, pb.x), ly = fmaxf(gtb.y, pb.y);
            float rx = fminf(gtb.z, pb.z), ry = fminf(gtb.w, pb.w);
            float w = fmaxf(rx - lx, 0.0f), h = fmaxf(ry - ly, 0.0f);
            float ov = w * h;
            float ga = (gtb.z - gtb.x) * (gtb.w - gtb.y);
            float pa = (pb.z - pb.x) * (pb.w - pb.y);
            iou_w = ov / (ga + pa - ov + 1e-9f);          // EPS_YOLOV6
        }

        out[bp] = (float)label;                           // labels
        ((float4*)(out + (size_t)BS * NP))[bp] = gtb;     // bboxes
        out[(size_t)BS * NP * 85 + bp] = fgm ? 1.0f : 0.0f;  // fg_mask

        s_plab[pl] = label;
        s_piou[pl] = iou_w;
    }
    __syncthreads();

    // scores: block's region is [pbase*80, (pbase+CHUNK)*80) floats of batch b
    // -> contiguous, 16B-aligned (525*80*4 = 168000 bytes), coalesced f4.
    float4* o4 = (float4*)(out + (size_t)BS * NP * 5 + ((size_t)b * NP + pbase) * 80);
    for (int q = tid; q < CHUNK * 20; q += NTHR) {
        int pl   = q / 20;          // local prior
        int comp = q - pl * 20;     // float4 slot within the 80-class row
        int lab  = s_plab[pl];
        float iw = s_piou[pl];
        int dd = lab - comp * 4;
        float4 v;
        v.x = (dd == 0) ? iw : 0.0f;
        v.y = (dd == 1) ? iw : 0.0f;
        v.z = (dd == 2) ? iw : 0.0f;
        v.w = (dd == 3) ? iw : 0.0f;
        o4[q] = v;
    }
}

extern "C" void kernel_launch(void* const* d_in, const int* in_sizes, int n_in,
                              void* d_out, int out_size, void* d_ws, size_t ws_size,
                              hipStream_t stream) {
    const float4* pred_bboxes = (const float4*)d_in[0];  // (32,8400,4) f32
    const float4* priors      = (const float4*)d_in[1];  // (8400,4)    f32
    const int*    gt_labels   = (const int*)d_in[2];     // (32,64,1)   i32
    const float4* gt_bboxes   = (const float4*)d_in[3];  // (32,64,4)   f32
    const float*  pad_flag    = (const float*)d_in[4];   // (32,64,1)   f32
    // d_in[5] = num_level_priors (6400,1600,400) — static, hard-coded.

    unsigned long long* posbits = (unsigned long long*)d_ws;  // 2.15 MB
    float* out = (float*)d_out;

    void* args[] = {
        (void*)&gt_bboxes, (void*)&pad_flag, (void*)&priors,
        (void*)&gt_labels, (void*)&pred_bboxes, (void*)&posbits, (void*)&out
    };
    // ONE enqueued op (was 4): R1->R4 delta analysis puts per-op cost ~12us.
    hipLaunchCooperativeKernel((const void*)k_fused, dim3(NBLK), dim3(NTHR),
                               args, 0, stream);
}

// Round 6
// 125.054 us; speedup vs baseline: 1.8466x; 1.8466x over previous
//
#include <hip/hip_runtime.h>

// Problem constants (fixed by setup_inputs in the reference).
#define BS 32
#define NG 64            // num_gt
#define NP 8400          // num_priors
#define NTOPK 9
#define NUM_CLASSES 80
#define NCAND 27         // 3 levels * TOPK

// ---------------------------------------------------------------------------
// Kernel 1: one WAVE per (b, g); 512 blocks x 256 (2048 waves, whole chip).
// Selection/threshold arithmetic VERBATIM from the R1/R4/R5-verified body
// (lanes 0-24 own the 5x5 window; 9 rounds of 5-step __shfl_xor butterfly min
// over packed key (dist_bits<<32|idx) == lax.top_k order; slot-order sum +
// ddof=1 variance -> thr bit-exact).
// OUTPUT CHANGE (replaces posbits+memset+global atomicOr): per-(b,g) list of
// 27 u32 slots — prior idx if that slot passes the full pos condition
// (pad>0 && ov>thr && center-inside-gt), else 0xFFFFFFFF. Every wave writes
// all 27 slots unconditionally -> workspace fully overwritten, no init.
// The downstream OR over (g,idx) pairs rebuilds the identical mask.
// ---------------------------------------------------------------------------
__device__ __forceinline__ unsigned long long wave_min_u64_32(unsigned long long k) {
    #pragma unroll
    for (int off = 1; off < 32; off <<= 1) {
        unsigned long long o = __shfl_xor(k, off, 64);
        k = (o < k) ? o : k;
    }
    return k;   // lanes 0-31 hold min over lanes 0-31 (keys live in 0-24)
}

__global__ __launch_bounds__(256) void k_candidates(
    const float4* __restrict__ gt_bboxes,    // (BS*NG)
    const float*  __restrict__ pad_flag,     // (BS*NG)
    unsigned int* __restrict__ cand)         // (BS*NG, NCAND) u32 slots
{
    const int bg   = (blockIdx.x * 256 + threadIdx.x) >> 6;  // wave id = (b,g)
    const int lane = threadIdx.x & 63;

    const float4 gt  = gt_bboxes[bg];        // wave-uniform broadcast load
    const float  pad = pad_flag[bg];
    const float  gcx = (gt.x + gt.z) * 0.5f;
    const float  gcy = (gt.y + gt.w) * 0.5f;
    const float  garea = (gt.z - gt.x) * (gt.w - gt.y);

    const float lvl_s[3] = {8.0f, 16.0f, 32.0f};
    const int   lvl_n[3] = {80, 40, 20};
    const int   lvl_b[3] = {0, 6400, 8000};

    float ov[NCAND];    // candidate IoUs, slot order (registers: static idx)
    int   ixs[NCAND];   // candidate prior indices
    float sum = 0.0f;

    const int dy5 = lane / 5;          // cell owned by this lane (lane<25)
    const int dx5 = lane - dy5 * 5;

    #pragma unroll
    for (int L = 0; L < 3; ++L) {
        const float s    = lvl_s[L];
        const int   n    = lvl_n[L];
        const int   base = lvl_b[L];

        int wx = (int)floorf(gcx / s) - 2;
        int wy = (int)floorf(gcy / s) - 2;
        wx = min(max(wx, 0), n - 5);
        wy = min(max(wy, 0), n - 5);

        // lane-parallel key build over the 5x5 window
        unsigned long long key = ~0ull;
        if (lane < 25) {
            const int   iy  = wy + dy5;
            const int   ix  = wx + dx5;
            const float py  = ((float)iy + 0.5f) * s;
            const float px  = ((float)ix + 0.5f) * s;
            const float ddx = gcx - px;
            const float ddy = gcy - py;
            const float d   = sqrtf(ddx * ddx + ddy * ddy);
            key = ((unsigned long long)__float_as_uint(d) << 32) |
                  (unsigned int)(base + iy * n + ix);
        }

        const float hx = s * 2.5f;
        #pragma unroll
        for (int q = 0; q < NTOPK; ++q) {
            const unsigned long long m = wave_min_u64_32(key);
            if (key == m) key = ~0ull;           // unique keys: one lane drops out

            // emit slot (ascending dist = lax.top_k order): IoU on all lanes
            const int slot = L * NTOPK + q;
            const int idx  = (int)(m & 0xffffffffu);
            const int rel  = idx - base;
            const int iy   = rel / n;            // n compile-time constant
            const int ix   = rel - iy * n;
            const float px = ((float)ix + 0.5f) * s;
            const float py = ((float)iy + 0.5f) * s;
            const float px0 = px - hx, py0 = py - hx;
            const float px1 = px + hx, py1 = py + hx;
            float lx = fmaxf(gt.x, px0), ly = fmaxf(gt.y, py0);
            float rx = fminf(gt.z, px1), ry = fminf(gt.w, py1);
            float w = fmaxf(rx - lx, 0.0f), h = fmaxf(ry - ly, 0.0f);
            float ovl = w * h;
            float parea = (px1 - px0) * (py1 - py0);
            float o = ovl / fmaxf(garea + parea - ovl, 1e-6f);  // EPS_OVERLAPS
            ov[slot]  = o;
            ixs[slot] = idx;
            sum += o;                             // slot-order accumulation
        }
    }

    const float mean = sum / (float)NCAND;
    float var = 0.0f;
    #pragma unroll
    for (int i = 0; i < NCAND; ++i) {
        float d = ov[i] - mean;
        var += d * d;
    }
    const float thr = mean + sqrtf(var / (float)(NCAND - 1));   // std ddof=1

    // per-slot pass condition (identical to the verified atomicOr guard);
    // lane i keeps slot i's verdict, then lanes 0-26 store coalesced.
    unsigned int myval = 0xFFFFFFFFu;
    if (pad > 0.0f) {
        #pragma unroll
        for (int i = 0; i < NCAND; ++i) {
            bool pass = false;
            if (ov[i] > thr) {
                const int   L    = i / NTOPK;     // static per unrolled i
                const float s    = lvl_s[L];
                const int   n    = lvl_n[L];
                const int   base = lvl_b[L];
                const int idx = ixs[i];
                const int rel = idx - base;
                const int iy  = rel / n;
                const int ix  = rel - iy * n;
                const float px = ((float)ix + 0.5f) * s;  // == cell center (exact)
                const float py = ((float)iy + 0.5f) * s;
                // prior center strictly inside gt box (> 1e-9)
                float mm = fminf(fminf(px - gt.x, py - gt.y),
                                 fminf(gt.z - px, gt.w - py));
                pass = (mm > 1e-9f);
            }
            if (lane == i && pass) myval = (unsigned int)ixs[i];
        }
    }
    if (lane < NCAND) cand[(size_t)bg * NCAND + lane] = myval;
}

// ---------------------------------------------------------------------------
// Kernel 2: regular launch, 33x32 blocks x 256 (the high-occupancy layout
// whose store stream ran fast in R3/R4 — R5 proved the cooperative 2-block/CU
// version throttles streaming stores to 0.8 TB/s).
// Step 1: invert this batch's candidate lists into a 256-prior LDS posbits
// tile (scan 1728 entries, ~7/thread, LDS atomicOr) — same (g,idx) OR-set as
// the verified global posbits, so masks are bit-identical.
// Step 2: resolve + write, VERBATIM the R1-verified k_assign semantics
// (conflict argmax first-max-wins, labels/bbox/fg, LDS-staged coalesced f4
// scores; plain stores — nontemporal regressed in the earlier session).
// ---------------------------------------------------------------------------
__global__ __launch_bounds__(256) void k_write(
    const float4* __restrict__ priors,
    const float4* __restrict__ gt_bboxes,
    const int*    __restrict__ gt_labels,
    const float4* __restrict__ pred_bboxes,
    const unsigned int* __restrict__ cand,
    float* __restrict__ out)
{
    __shared__ float4 s_gt[NG];
    __shared__ int    s_lab[NG];
    __shared__ unsigned long long s_pos[256];
    __shared__ int    s_plab[256];
    __shared__ float  s_piou[256];

    const int b   = blockIdx.y;
    const int tid = threadIdx.x;
    const int p0  = blockIdx.x * 256;

    if (tid < NG) {
        s_gt[tid]  = gt_bboxes[b * NG + tid];
        s_lab[tid] = gt_labels[b * NG + tid];
    }
    s_pos[tid] = 0;
    __syncthreads();

    // ---- invert candidate lists -> LDS posbits for priors [p0, p0+256) ----
    const unsigned int* bc = cand + (size_t)b * NG * NCAND;
    for (int e = tid; e < NG * NCAND; e += 256) {
        unsigned int idx = bc[e];
        unsigned int rel = idx - (unsigned int)p0;   // wraps if idx<p0 or idx==-1
        if (rel < 256u) {
            atomicOr(&s_pos[rel], 1ull << (e / NCAND));   // g = e/27
        }
    }
    __syncthreads();

    const int p = p0 + tid;
    int   label  = NUM_CLASSES;
    float iou_w  = 0.0f;

    if (p < NP) {
        const size_t bp = (size_t)b * NP + p;
        unsigned long long mask = s_pos[tid];
        int fg = __popcll(mask);
        int gidx = 0;

        if (fg > 1) {
            // conflict: argmax_g IoU(gt, prior_cell_box) over ALL gts, first
            // max wins (matches jnp.argmax(overlaps, axis=1) semantics).
            float4 pr = priors[p];
            float hx = pr.z * 2.5f, hy = pr.w * 2.5f;
            float px0 = pr.x - hx, py0 = pr.y - hy, px1 = pr.x + hx, py1 = pr.y + hy;
            float parea = (px1 - px0) * (py1 - py0);
            float best = -1.0f;
            for (int gg = 0; gg < NG; ++gg) {
                float4 gtb = s_gt[gg];
                float lx = fmaxf(gtb.x, px0), ly = fmaxf(gtb.y, py0);
                float rx = fminf(gtb.z, px1), ry = fminf(gtb.w, py1);
                float w = fmaxf(rx - lx, 0.0f), h = fmaxf(ry - ly, 0.0f);
                float ovl = w * h;
                float ga = (gtb.z - gtb.x) * (gtb.w - gtb.y);
                float v = ovl / fmaxf(ga + parea - ovl, 1e-6f);
                if (v > best) { best = v; gidx = gg; }
            }
        } else if (fg == 1) {
            gidx = __ffsll((unsigned long long)mask) - 1;
        }

        const bool   fgm = fg > 0;
        const float4 gtb = s_gt[gidx];   // gidx==0 for background (ref: argmax of zeros)
        label = fgm ? s_lab[gidx] : NUM_CLASSES;

        if (fgm) {
            float4 pb = pred_bboxes[bp];
            float lx = fmaxf(gtb.x, pb.x), ly = fmaxf(gtb.y, pb.y);
            float rx = fminf(gtb.z, pb.z), ry = fminf(gtb.w, pb.w);
            float w = fmaxf(rx - lx, 0.0f), h = fmaxf(ry - ly, 0.0f);
            float ov = w * h;
            float ga = (gtb.z - gtb.x) * (gtb.w - gtb.y);
            float pa = (pb.z - pb.x) * (pb.w - pb.y);
            iou_w = ov / (ga + pa - ov + 1e-9f);          // EPS_YOLOV6
        }

        out[bp] = (float)label;                           // labels
        ((float4*)(out + (size_t)BS * NP))[bp] = gtb;     // bboxes
        out[(size_t)BS * NP * 85 + bp] = fgm ? 1.0f : 0.0f;  // fg_mask
    }

    s_plab[tid] = label;
    s_piou[tid] = iou_w;
    __syncthreads();

    // scores: block's region is [p0*80, (p0+npr)*80) floats -> coalesced f4
    const int npr  = min(256, NP - p0);
    const int nfl4 = npr * 20;
    float4* o4 = (float4*)(out + (size_t)BS * NP * 5 + ((size_t)b * NP + p0) * 80);
    for (int q = tid; q < nfl4; q += 256) {
        int pl   = q / 20;          // local prior
        int comp = q - pl * 20;     // float4 slot within the 80-class row
        int lab  = s_plab[pl];
        float iw = s_piou[pl];
        int dd = lab - comp * 4;
        float4 v;
        v.x = (dd == 0) ? iw : 0.0f;
        v.y = (dd == 1) ? iw : 0.0f;
        v.z = (dd == 2) ? iw : 0.0f;
        v.w = (dd == 3) ? iw : 0.0f;
        o4[q] = v;
    }
}

extern "C" void kernel_launch(void* const* d_in, const int* in_sizes, int n_in,
                              void* d_out, int out_size, void* d_ws, size_t ws_size,
                              hipStream_t stream) {
    const float4* pred_bboxes = (const float4*)d_in[0];  // (32,8400,4) f32
    const float4* priors      = (const float4*)d_in[1];  // (8400,4)    f32
    const int*    gt_labels   = (const int*)d_in[2];     // (32,64,1)   i32
    const float4* gt_bboxes   = (const float4*)d_in[3];  // (32,64,4)   f32
    const float*  pad_flag    = (const float*)d_in[4];   // (32,64,1)   f32
    // d_in[5] = num_level_priors (6400,1600,400) — static, hard-coded.

    unsigned int* cand = (unsigned int*)d_ws;   // 221 KB, fully overwritten

    // TWO regular dispatches, no memset (R5: cooperative fixed cost ~+43us;
    // R1-R4 fit: total ~= 66 + sum(max(kernel, ~12us)) per dispatch).
    k_candidates<<<dim3(BS * NG * 64 / 256), dim3(256), 0, stream>>>(
        gt_bboxes, pad_flag, cand);

    k_write<<<dim3((NP + 255) / 256, BS), dim3(256), 0, stream>>>(
        priors, gt_bboxes, gt_labels, pred_bboxes, cand, (float*)d_out);
}